// Round 10
// baseline (418.888 us; speedup 1.0000x reference)
//
#include <hip/hip_runtime.h>

#define B_  2
#define T_  2048
#define H_  1024
#define NH_ 16
#define HD_ 64
#define M_  (B_*T_)   // 4096 rows
#define PS_ 72        // P-matrix LDS row stride (64 data + 8 pad)

typedef __bf16 bf16x8 __attribute__((ext_vector_type(8)));
typedef float  floatx4 __attribute__((ext_vector_type(4)));

typedef __attribute__((address_space(1))) const unsigned int gas_u32;
typedef __attribute__((address_space(3))) unsigned int       las_u32;

__device__ __forceinline__ void gload_lds16(const __bf16* g, __bf16* l) {
    __builtin_amdgcn_global_load_lds((gas_u32*)g, (las_u32*)l, 16, 0, 0);
}

// ---------------------------------------------------------------- transpose (f32 -> bf16)
__global__ __launch_bounds__(256) void transpose_bf16(
    const float* __restrict__ in, __bf16* __restrict__ out, int K, int N)
{
    __shared__ float tile[32][33];
    const int k0 = blockIdx.x * 32, n0 = blockIdx.y * 32;
    const int tx = threadIdx.x & 31, ty = threadIdx.x >> 5;
#pragma unroll
    for (int i = 0; i < 32; i += 8)
        tile[ty + i][tx] = in[(size_t)(k0 + ty + i) * N + (n0 + tx)];
    __syncthreads();
#pragma unroll
    for (int i = 0; i < 32; i += 8)
        out[(size_t)(n0 + ty + i) * K + (k0 + tx)] = (__bf16)tile[tx][ty + i];
}

// ---------------------------------------------------------------- transpose V (bf16 -> bf16)
__global__ __launch_bounds__(256) void transpose_v(
    const __bf16* __restrict__ vb, __bf16* __restrict__ vtb)
{
    __shared__ __bf16 tile[32][33];
    const int bh = blockIdx.x;
    const int t0 = blockIdx.y * 32, d0 = blockIdx.z * 32;
    const __bf16* src = vb  + (size_t)bh * T_ * HD_;
    __bf16*       dst = vtb + (size_t)bh * HD_ * T_;
    const int tx = threadIdx.x & 31, ty = threadIdx.x >> 5;
#pragma unroll
    for (int i = 0; i < 32; i += 8)
        tile[ty + i][tx] = src[(size_t)(t0 + ty + i) * HD_ + (d0 + tx)];
    __syncthreads();
#pragma unroll
    for (int i = 0; i < 32; i += 8)
        dst[(size_t)(d0 + ty + i) * T_ + (t0 + tx)] = tile[tx][ty + i];
}

// ---------------------------------------------------------------- group norm (3-stage)
__global__ __launch_bounds__(256) void gn_partial(
    const float* __restrict__ x, float2* __restrict__ part)
{
    const int bg = blockIdx.x, chunk = blockIdx.y;
    const int batch = bg >> 5, g = bg & 31;
    const float* xp = x + (size_t)batch * T_ * H_ + g * 32;
    float s = 0.f, ss = 0.f;
    for (int i = threadIdx.x; i < 128 * 32; i += 256) {
        const int t = chunk * 128 + (i >> 5), c = i & 31;
        const float v = xp[(size_t)t * H_ + c];
        s += v; ss += v * v;
    }
#pragma unroll
    for (int off = 32; off > 0; off >>= 1) {
        s  += __shfl_down(s,  off, 64);
        ss += __shfl_down(ss, off, 64);
    }
    __shared__ float rs[4], rss[4];
    const int wv = threadIdx.x >> 6, lane = threadIdx.x & 63;
    if (lane == 0) { rs[wv] = s; rss[wv] = ss; }
    __syncthreads();
    if (threadIdx.x == 0)
        part[bg * 16 + chunk] =
            make_float2(rs[0] + rs[1] + rs[2] + rs[3],
                        rss[0] + rss[1] + rss[2] + rss[3]);
}

__global__ __launch_bounds__(64) void gn_finalize(
    const float2* __restrict__ part, float2* __restrict__ stats)
{
    const int bg = threadIdx.x;
    float s = 0.f, ss = 0.f;
#pragma unroll
    for (int i = 0; i < 16; ++i) {
        const float2 p = part[bg * 16 + i];
        s += p.x; ss += p.y;
    }
    const float inv = 1.f / (float)(T_ * 32);
    const float mean = s * inv;
    const float var  = ss * inv - mean * mean;
    stats[bg] = make_float2(mean, rsqrtf(var + 1e-5f));
}

__global__ __launch_bounds__(256) void gn_apply(
    const float* __restrict__ x, const float2* __restrict__ stats,
    const float* __restrict__ w, const float* __restrict__ bsc,
    __bf16* __restrict__ out)
{
    const size_t idx = ((size_t)blockIdx.x * 256 + threadIdx.x) * 4;
    const int h = (int)(idx & (H_ - 1));
    const int batch = (int)(idx >> 21);          // T_*H_ = 2^21
    const float2 mr = stats[batch * 32 + (h >> 5)];
    const float4 xv = *(const float4*)(x + idx);
    const float4 wv = *(const float4*)(w + h);
    const float4 bv = *(const float4*)(bsc + h);
    __bf16 o[4];
    o[0] = (__bf16)((xv.x - mr.x) * mr.y * wv.x + bv.x);
    o[1] = (__bf16)((xv.y - mr.x) * mr.y * wv.y + bv.y);
    o[2] = (__bf16)((xv.z - mr.x) * mr.y * wv.z + bv.z);
    o[3] = (__bf16)((xv.w - mr.x) * mr.y * wv.w + bv.w);
    *(uint2*)(out + idx) = *(uint2*)o;
}

// ---------------------------------------------------------------- GEMM core 256x256
// 512 threads = 8 waves (2M x 4N). BK=32, FOUR 32KB buffers (128 KB ring):
// stage tile j+3 while computing j; vmcnt(12) steady (3 tiles of latency
// cover), tail 8/4/0. T2 swizzle + T5 setprio. (R8-verified.)
__device__ __forceinline__ void gemm_core256(
    const __bf16* __restrict__ A, const __bf16* __restrict__ BT,
    int K, int m0, int n0, __bf16* Sb, floatx4 (&acc)[8][4])
{
    const int tid = threadIdx.x, lane = tid & 63, wid = tid >> 6;
    const int quad = lane >> 4, l16 = lane & 15;
    const int wm = (wid >> 2) * 128, wn = (wid & 3) * 64;
    const int r0 = tid >> 2, cbs = tid & 3;
    const int sc  = ((cbs ^ ((r0 >> 1) & 3)) * 8);   // swizzled stage col
    const int xq8 = (quad ^ ((l16 >> 1) & 3)) * 8;   // swizzled read col

    const __bf16* Ag = A  + (size_t)(m0 + r0) * K + sc;
    const __bf16* Bg = BT + (size_t)(n0 + r0) * K + sc;

#define STG256(b, kt)  do {                                                   \
    gload_lds16(Ag + (kt),                  Sb + (b)*16384 + tid*8);          \
    gload_lds16(Ag + (size_t)128*K + (kt),  Sb + (b)*16384 + 4096 + tid*8);   \
    gload_lds16(Bg + (kt),                  Sb + (b)*16384 + 8192 + tid*8);   \
    gload_lds16(Bg + (size_t)128*K + (kt),  Sb + (b)*16384 + 12288 + tid*8); } while (0)

    const int NT = K >> 5;
    STG256(0, 0);
    STG256(1, 32);
    STG256(2, 64);
    int cur = 0;
    for (int j = 0; j < NT; ++j) {
        const int kt = j << 5;
        if (j + 3 < NT) {                      // stage tile j+3, counted wait
            STG256((cur + 3) & 3, kt + 96);
            asm volatile("s_waitcnt vmcnt(12)" ::: "memory");  // tile j landed
        } else if (j + 2 < NT) {
            asm volatile("s_waitcnt vmcnt(8)" ::: "memory");
        } else if (j + 1 < NT) {
            asm volatile("s_waitcnt vmcnt(4)" ::: "memory");
        } else {
            asm volatile("s_waitcnt vmcnt(0)" ::: "memory");
        }
        __builtin_amdgcn_s_barrier();          // all waves: buf[cur] ready
        __builtin_amdgcn_sched_barrier(0);
        const __bf16* Ab = Sb + cur * 16384;
        const __bf16* Bb = Sb + cur * 16384 + 8192;
        bf16x8 af[8], bfg[4];
#pragma unroll
        for (int i = 0; i < 8; ++i)
            af[i]  = *(const bf16x8*)(Ab + (wm + i * 16 + l16) * 32 + xq8);
#pragma unroll
        for (int i = 0; i < 4; ++i)
            bfg[i] = *(const bf16x8*)(Bb + (wn + i * 16 + l16) * 32 + xq8);
        __builtin_amdgcn_s_setprio(1);
#pragma unroll
        for (int mi = 0; mi < 8; ++mi)
#pragma unroll
            for (int ni = 0; ni < 4; ++ni)
                acc[mi][ni] = __builtin_amdgcn_mfma_f32_16x16x32_bf16(
                    af[mi], bfg[ni], acc[mi][ni], 0, 0, 0);
        __builtin_amdgcn_s_setprio(0);
        __builtin_amdgcn_sched_barrier(0);     // keep reads above the barrier
        __builtin_amdgcn_s_barrier();          // reads of buf[cur] done
        __builtin_amdgcn_sched_barrier(0);     // keep next staging below
        cur = (cur + 1) & 3;
    }
#undef STG256
}

#define GEMM256_PROLOGUE(KVAL)                                          \
    __shared__ __align__(16) __bf16 Sb[4 * 16384];  /* 128 KB */        \
    const int m0 = blockIdx.x * 256, n0 = blockIdx.y * 256;             \
    floatx4 acc[8][4];                                                  \
    { floatx4 z = {0.f, 0.f, 0.f, 0.f};                                 \
      for (int i = 0; i < 8; ++i) for (int j = 0; j < 4; ++j) acc[i][j] = z; } \
    gemm_core256(A, BT, (KVAL), m0, n0, Sb, acc);                       \
    const int tid = threadIdx.x, lane = tid & 63, wid = tid >> 6;       \
    const int quad = lane >> 4, l16 = lane & 15;                        \
    const int wm = (wid >> 2) * 128, wn = (wid & 3) * 64;               \
    (void)tid;

// QKV: q (pre-scaled by log2 e), k, v written coalesced [B,NH,T,HD];
// present fp32. v's transposed copy is produced by transpose_v afterwards.
__global__ __launch_bounds__(512) void gemm_qkv(
    const __bf16* __restrict__ A, const __bf16* __restrict__ BT,
    const float* __restrict__ bias, __bf16* __restrict__ qb,
    __bf16* __restrict__ kb, __bf16* __restrict__ vb,
    float* __restrict__ present)
{
    GEMM256_PROLOGUE(H_)
#pragma unroll
    for (int ni = 0; ni < 4; ++ni) {
        const int col = n0 + wn + ni * 16 + l16;
        const float bv = bias[col];
        const int which = col >> 10, c = col & 1023, hh = c >> 6, d = c & 63;
#pragma unroll
        for (int mi = 0; mi < 8; ++mi)
#pragma unroll
            for (int r = 0; r < 4; ++r) {
                const int row = m0 + wm + mi * 16 + quad * 4 + r;
                const int bb = row >> 11, t = row & 2047;
                const float v = acc[mi][ni][r] + bv;
                const size_t idx = (((size_t)bb * NH_ + hh) * T_ + t) * HD_ + d;
                if (which == 0)      qb[idx] = (__bf16)(v * 1.4426950408889634f);
                else if (which == 1) { kb[idx] = (__bf16)v; present[idx] = v; }
                else { vb[idx] = (__bf16)v;
                       present[(size_t)B_ * NH_ * T_ * HD_ + idx] = v; }
            }
    }
}

// gelu via sigmoid identity: 0.5v(1+tanh(u)) = v * sigmoid(2u)
__global__ __launch_bounds__(512) void gemm_gelu(
    const __bf16* __restrict__ A, const __bf16* __restrict__ BT,
    const float* __restrict__ bias, __bf16* __restrict__ out)
{
    GEMM256_PROLOGUE(H_)
#pragma unroll
    for (int ni = 0; ni < 4; ++ni) {
        const int col = n0 + wn + ni * 16 + l16;
        const float bv = bias[col];
#pragma unroll
        for (int mi = 0; mi < 8; ++mi)
#pragma unroll
            for (int r = 0; r < 4; ++r) {
                const int row = m0 + wm + mi * 16 + quad * 4 + r;
                const float v = acc[mi][ni][r] + bv;
                const float e = exp2f(-2.3022082f * (v + 0.044715f * v * v * v));
                float rcp;
                asm("v_rcp_f32 %0, %1" : "=v"(rcp) : "v"(1.f + e));
                out[(size_t)row * (4 * H_) + col] = (__bf16)(v * rcp);
            }
    }
}

// ---------------------------------------------------------------- GEMM 128x128 + resid
// 32 MFMA/wave per K-step (BK=32), ring-3 (48 KB LDS -> 3 blocks/CU),
// vmcnt(8) lookahead-2, grid exactly 256 blocks for N=1024. T2 swizzle.
__global__ __launch_bounds__(256) void gemm_resid_128(
    const __bf16* __restrict__ A, const __bf16* __restrict__ BT,
    const float* __restrict__ bias, const float* __restrict__ resid,
    float* __restrict__ out, int K, int N)
{
    __shared__ __align__(16) __bf16 As[3 * 4096], Bs[3 * 4096];  // 48 KB
    const int m0 = blockIdx.x * 128, n0 = blockIdx.y * 128;
    const int tid  = threadIdx.x;
    const int lane = tid & 63, wv = tid >> 6;
    const int quad = lane >> 4, l16 = lane & 15;
    const int wm = (wv >> 1) * 64, wn = (wv & 1) * 64;
    const int r0 = tid >> 2;
    const int scs = (((tid & 3) ^ ((r0 >> 1) & 3)) * 8);
    const int xq8 = (quad ^ ((l16 >> 1) & 3)) * 8;

    floatx4 acc[4][4];
    { floatx4 z = {0.f, 0.f, 0.f, 0.f};
#pragma unroll
      for (int i = 0; i < 4; ++i)
#pragma unroll
          for (int j = 0; j < 4; ++j) acc[i][j] = z; }

    const __bf16* Ag = A  + (size_t)(m0 + r0) * K + scs;
    const __bf16* Bg = BT + (size_t)(n0 + r0) * K + scs;

#define STGR3(b, kt)  do {                                                    \
    gload_lds16(Ag + (kt),                  As + (b)*4096 + tid*8);           \
    gload_lds16(Ag + (size_t)64 * K + (kt), As + (b)*4096 + 2048 + tid*8);    \
    gload_lds16(Bg + (kt),                  Bs + (b)*4096 + tid*8);           \
    gload_lds16(Bg + (size_t)64 * K + (kt), Bs + (b)*4096 + 2048 + tid*8); } while (0)

    const int NT = K >> 5;                     // BK = 32
    STGR3(0, 0);
    STGR3(1, 32);
    int cur = 0;
    for (int j = 0; j < NT; ++j) {
        const int kt = j << 5;
        if (j + 2 < NT) {                      // stage tile j+2, counted wait
            int nb = cur + 2; if (nb >= 3) nb -= 3;
            STGR3(nb, kt + 64);
            asm volatile("s_waitcnt vmcnt(8)" ::: "memory");   // tile j landed
        } else if (j + 1 < NT) {
            asm volatile("s_waitcnt vmcnt(4)" ::: "memory");
        } else {
            asm volatile("s_waitcnt vmcnt(0)" ::: "memory");
        }
        __builtin_amdgcn_s_barrier();
        __builtin_amdgcn_sched_barrier(0);
        const __bf16* Ab = As + cur * 4096;
        const __bf16* Bb = Bs + cur * 4096;
        bf16x8 af[4], bfg[4];
#pragma unroll
        for (int i = 0; i < 4; ++i)
            af[i]  = *(const bf16x8*)(Ab + (wm + i * 16 + l16) * 32 + xq8);
#pragma unroll
        for (int i = 0; i < 4; ++i)
            bfg[i] = *(const bf16x8*)(Bb + (wn + i * 16 + l16) * 32 + xq8);
        __builtin_amdgcn_s_setprio(1);
#pragma unroll
        for (int mi = 0; mi < 4; ++mi)
#pragma unroll
            for (int ni = 0; ni < 4; ++ni)
                acc[mi][ni] = __builtin_amdgcn_mfma_f32_16x16x32_bf16(
                    af[mi], bfg[ni], acc[mi][ni], 0, 0, 0);
        __builtin_amdgcn_s_setprio(0);
        __builtin_amdgcn_sched_barrier(0);
        __builtin_amdgcn_s_barrier();
        __builtin_amdgcn_sched_barrier(0);
        cur = cur + 1; if (cur >= 3) cur = 0;
    }
#undef STGR3

#pragma unroll
    for (int ni = 0; ni < 4; ++ni) {
        const int col = n0 + wn + ni * 16 + l16;
        const float bv = bias[col];
#pragma unroll
        for (int mi = 0; mi < 4; ++mi)
#pragma unroll
            for (int r = 0; r < 4; ++r) {
                const int row = m0 + wm + mi * 16 + quad * 4 + r;
                const size_t idx = (size_t)row * N + col;
                out[idx] = acc[mi][ni][r] + bv + resid[idx];
            }
    }
}

// ---------------------------------------------------------------- attention v3
// v2 + lane-local defer-max: the cross-lane row-max shuffle reduce runs ONLY
// when the rescale triggers (rare). Trigger condition is exactly equivalent:
// any row's true max > m+8  <=>  any lane's local max > m+8 (__any = OR).
__global__ __launch_bounds__(256) void attn_kernel(
    const __bf16* __restrict__ qb, const __bf16* __restrict__ kb,
    const __bf16* __restrict__ vtb, __bf16* __restrict__ aout)
{
    const int bh = blockIdx.x;
    const int sp = 31 - blockIdx.y;          // LPT: longest blocks dispatched first
    const int bb = bh >> 4, hh = bh & 15;
    const __bf16* Q  = qb  + (size_t)bh * T_ * HD_;
    const __bf16* Kp = kb  + (size_t)bh * T_ * HD_;
    const __bf16* VT = vtb + (size_t)bh * HD_ * T_;
    __shared__ __align__(16) __bf16 Qs[2 * 2048];
    __shared__ __align__(16) __bf16 Ks[2][2 * 2048];
    __shared__ __align__(16) __bf16 Vs[2][2 * 2048];
    __shared__ __align__(16) __bf16 Ps[64 * PS_];

    const int tid = threadIdx.x, lane = tid & 63, wv = tid >> 6;
    const int quad = lane >> 4, l16 = lane & 15;
    const int sr = tid >> 2;                              // staging row 0..63
    const int scs = (((tid & 3) ^ ((sr >> 1) & 3)) * 8);  // swizzled stage col
    const int xq8 = (quad ^ ((l16 >> 1) & 3)) * 8;        // swizzled read col

    const int q0 = sp * 64, nkt = sp + 1;

    // prologue: stage Q + K/V tile 0, drain, hoist Q to regs
#pragma unroll
    for (int s = 0; s < 2; ++s) {
        gload_lds16(Q  + (size_t)(q0 + sr) * HD_ + s * 32 + scs, Qs + s * 2048 + tid * 8);
        gload_lds16(Kp + (size_t)sr * HD_ + s * 32 + scs, &Ks[0][s * 2048 + tid * 8]);
        gload_lds16(VT + (size_t)sr * T_  + s * 32 + scs, &Vs[0][s * 2048 + tid * 8]);
    }
    asm volatile("s_waitcnt vmcnt(0)" ::: "memory");
    __builtin_amdgcn_s_barrier();
    __builtin_amdgcn_sched_barrier(0);

    bf16x8 aq[2];
#pragma unroll
    for (int kk = 0; kk < 2; ++kk)
        aq[kk] = *(const bf16x8*)(Qs + kk * 2048 + (wv * 16 + l16) * 32 + xq8);

    float m_i[4], l_p[4];
    floatx4 Ov[4];
    { floatx4 z = {0.f, 0.f, 0.f, 0.f};
#pragma unroll
      for (int i = 0; i < 4; ++i) { Ov[i] = z; m_i[i] = -1e30f; l_p[i] = 0.f; } }

    int cur = 0;
    for (int kt = 0; kt < nkt; ++kt) {
        if (kt + 1 < nkt) {
            const int kn = (kt + 1) * 64;
#pragma unroll
            for (int s = 0; s < 2; ++s) {
                gload_lds16(Kp + (size_t)(kn + sr) * HD_ + s * 32 + scs,
                            &Ks[cur ^ 1][s * 2048 + tid * 8]);
                gload_lds16(VT + (size_t)sr * T_ + kn + s * 32 + scs,
                            &Vs[cur ^ 1][s * 2048 + tid * 8]);
            }
            asm volatile("s_waitcnt vmcnt(4)" ::: "memory");   // tile kt landed
        } else {
            asm volatile("s_waitcnt vmcnt(0)" ::: "memory");
        }
        __builtin_amdgcn_s_barrier();          // all waves: buf[cur] ready
        __builtin_amdgcn_sched_barrier(0);

        const __bf16* Kc = Ks[cur];
        const __bf16* Vc = Vs[cur];

        // S = Q K^T (log2-domain scores)
        floatx4 sacc[4];
        { floatx4 z = {0.f, 0.f, 0.f, 0.f};
#pragma unroll
          for (int i = 0; i < 4; ++i) sacc[i] = z; }
#pragma unroll
        for (int kk = 0; kk < 2; ++kk)
#pragma unroll
            for (int ni = 0; ni < 4; ++ni) {
                const bf16x8 bk = *(const bf16x8*)(Kc + kk * 2048 + (ni * 16 + l16) * 32 + xq8);
                sacc[ni] = __builtin_amdgcn_mfma_f32_16x16x32_bf16(aq[kk], bk, sacc[ni], 0, 0, 0);
            }
        if (kt == sp) {    // diagonal tile: causal mask (local coords)
#pragma unroll
            for (int ni = 0; ni < 4; ++ni) {
                const int keyL = ni * 16 + l16;
#pragma unroll
                for (int r = 0; r < 4; ++r)
                    if (keyL > quad * 4 + r + wv * 16) sacc[ni][r] = -1e30f;
            }
        }
        // defer-max, lane-local trigger: shuffles only when rescale needed
        float rml[4];
#pragma unroll
        for (int r = 0; r < 4; ++r)
            rml[r] = fmaxf(fmaxf(sacc[0][r], sacc[1][r]),
                           fmaxf(sacc[2][r], sacc[3][r]));
        float need = rml[0] - m_i[0];
#pragma unroll
        for (int r = 1; r < 4; ++r) need = fmaxf(need, rml[r] - m_i[r]);
        if (__any(need > 8.f)) {               // rare: exact row max + rescale
#pragma unroll
            for (int off = 1; off < 16; off <<= 1)
#pragma unroll
                for (int r = 0; r < 4; ++r)
                    rml[r] = fmaxf(rml[r], __shfl_xor(rml[r], off, 64));
#pragma unroll
            for (int r = 0; r < 4; ++r) {
                const float mn = fmaxf(m_i[r], rml[r]);
                const float al = exp2f(m_i[r] - mn);
                m_i[r] = mn;
                l_p[r] *= al;
#pragma unroll
                for (int ni = 0; ni < 4; ++ni) Ov[ni][r] *= al;
            }
        }
#pragma unroll
        for (int ni = 0; ni < 4; ++ni)
#pragma unroll
            for (int r = 0; r < 4; ++r) {
                const float pe = exp2f(sacc[ni][r] - m_i[r]);
                sacc[ni][r] = pe;
                l_p[r] += pe;                  // lane-partial; reduced at end
            }
        // P: C-layout -> A-layout via wave-private LDS rows (stride 72)
#pragma unroll
        for (int ni = 0; ni < 4; ++ni)
#pragma unroll
            for (int r = 0; r < 4; ++r)
                Ps[(wv * 16 + quad * 4 + r) * PS_ + ni * 16 + l16] = (__bf16)sacc[ni][r];
        // O += P V
#pragma unroll
        for (int kk = 0; kk < 2; ++kk) {
            const bf16x8 ap = *(const bf16x8*)(Ps + (wv * 16 + l16) * PS_ + kk * 32 + quad * 8);
#pragma unroll
            for (int ni = 0; ni < 4; ++ni) {
                const bf16x8 bv2 = *(const bf16x8*)(Vc + kk * 2048 + (ni * 16 + l16) * 32 + xq8);
                Ov[ni] = __builtin_amdgcn_mfma_f32_16x16x32_bf16(ap, bv2, Ov[ni], 0, 0, 0);
            }
        }
        __builtin_amdgcn_sched_barrier(0);     // keep reads above the barrier
        __builtin_amdgcn_s_barrier();          // reads of buf[cur] done
        __builtin_amdgcn_sched_barrier(0);     // keep next staging below
        cur ^= 1;
    }
    // epilogue: reduce lane-partial l across the 16 key-lanes, then store
#pragma unroll
    for (int off = 1; off < 16; off <<= 1)
#pragma unroll
        for (int r = 0; r < 4; ++r)
            l_p[r] += __shfl_xor(l_p[r], off, 64);
#pragma unroll
    for (int ni = 0; ni < 4; ++ni)
#pragma unroll
        for (int r = 0; r < 4; ++r) {
            const int t = q0 + wv * 16 + quad * 4 + r;
            aout[((size_t)(bb * T_ + t)) * H_ + hh * HD_ + ni * 16 + l16] =
                (__bf16)(Ov[ni][r] / l_p[r]);
        }
}

// ---------------------------------------------------------------- launch
extern "C" void kernel_launch(void* const* d_in, const int* in_sizes, int n_in,
                              void* d_out, int out_size, void* d_ws, size_t ws_size,
                              hipStream_t stream)
{
    (void)in_sizes; (void)n_in; (void)out_size; (void)ws_size;
    const float* x       = (const float*)d_in[0];
    const float* w_attn  = (const float*)d_in[1];
    const float* b_attn  = (const float*)d_in[2];
    const float* w_aproj = (const float*)d_in[3];
    const float* b_aproj = (const float*)d_in[4];
    const float* ln1_w   = (const float*)d_in[5];
    const float* ln1_b   = (const float*)d_in[6];
    const float* ln2_w   = (const float*)d_in[7];
    const float* ln2_b   = (const float*)d_in[8];
    const float* w_fc    = (const float*)d_in[9];
    const float* b_fc    = (const float*)d_in[10];
    const float* w_mproj = (const float*)d_in[11];
    const float* b_mproj = (const float*)d_in[12];
    float* out = (float*)d_out;
    float* present = out + (size_t)M_ * H_;

    char* wp = (char*)d_ws;
    auto alloc = [&](size_t bytes) {
        void* p = (void*)wp; wp += (bytes + 255) & ~(size_t)255; return p;
    };
    __bf16* A1       = (__bf16*)alloc((size_t)M_ * H_ * 2);
    __bf16* A2       = (__bf16*)alloc((size_t)M_ * H_ * 2);
    __bf16* WattnT   = (__bf16*)alloc((size_t)3 * H_ * H_ * 2);
    __bf16* WaprojT  = (__bf16*)alloc((size_t)H_ * H_ * 2);
    __bf16* WfcT     = (__bf16*)alloc((size_t)4 * H_ * H_ * 2);
    __bf16* WmprojT  = (__bf16*)alloc((size_t)4 * H_ * H_ * 2);
    __bf16* qb       = (__bf16*)alloc((size_t)M_ * H_ * 2);
    __bf16* kb       = (__bf16*)alloc((size_t)M_ * H_ * 2);
    __bf16* vb       = (__bf16*)alloc((size_t)M_ * H_ * 2);
    __bf16* vtb      = (__bf16*)alloc((size_t)M_ * H_ * 2);
    __bf16* attn_out = (__bf16*)alloc((size_t)M_ * H_ * 2);
    float*  x2       = (float*) alloc((size_t)M_ * H_ * 4);
    __bf16* Hbuf     = (__bf16*)alloc((size_t)M_ * 4 * H_ * 2);
    float2* gn_part  = (float2*)alloc(64 * 16 * sizeof(float2));
    float2* gn_stats = (float2*)alloc(64 * sizeof(float2));

    transpose_bf16<<<dim3(H_/32, 3*H_/32), 256, 0, stream>>>(w_attn,  WattnT,  H_,   3*H_);
    transpose_bf16<<<dim3(H_/32, H_/32),   256, 0, stream>>>(w_aproj, WaprojT, H_,   H_);
    transpose_bf16<<<dim3(H_/32, 4*H_/32), 256, 0, stream>>>(w_fc,    WfcT,    H_,   4*H_);
    transpose_bf16<<<dim3(4*H_/32, H_/32), 256, 0, stream>>>(w_mproj, WmprojT, 4*H_, H_);

    gn_partial <<<dim3(64, 16), 256, 0, stream>>>(x, gn_part);
    gn_finalize<<<1, 64, 0, stream>>>(gn_part, gn_stats);
    gn_apply   <<<M_*H_/1024, 256, 0, stream>>>(x, gn_stats, ln1_w, ln1_b, A1);

    gemm_qkv<<<dim3(M_/256, 3*H_/256), 512, 0, stream>>>(A1, WattnT, b_attn,
                                                         qb, kb, vb, present);
    transpose_v<<<dim3(B_*NH_, T_/32, HD_/32), 256, 0, stream>>>(vb, vtb);
    attn_kernel<<<dim3(32, 32), 256, 0, stream>>>(qb, kb, vtb, attn_out);
    gemm_resid_128<<<dim3(M_/128, H_/128), 256, 0, stream>>>(attn_out, WaprojT, b_aproj,
                                                             x, x2, H_, H_);

    gn_partial <<<dim3(64, 16), 256, 0, stream>>>(x2, gn_part);
    gn_finalize<<<1, 64, 0, stream>>>(gn_part, gn_stats);
    gn_apply   <<<M_*H_/1024, 256, 0, stream>>>(x2, gn_stats, ln2_w, ln2_b, A2);

    gemm_gelu<<<dim3(M_/256, 4*H_/256), 512, 0, stream>>>(A2, WfcT, b_fc, Hbuf);
    gemm_resid_128<<<dim3(M_/128, H_/128), 256, 0, stream>>>(Hbuf, WmprojT, b_mproj,
                                                             x2, out, 4*H_, H_);
}

// Round 11
// 400.902 us; speedup vs baseline: 1.0449x; 1.0449x over previous
//
#include <hip/hip_runtime.h>

#define B_  2
#define T_  2048
#define H_  1024
#define NH_ 16
#define HD_ 64
#define M_  (B_*T_)   // 4096 rows
#define PS_ 72        // P-matrix LDS row stride (64 data + 8 pad)

typedef __bf16 bf16x8 __attribute__((ext_vector_type(8)));
typedef float  floatx4 __attribute__((ext_vector_type(4)));

typedef __attribute__((address_space(1))) const unsigned int gas_u32;
typedef __attribute__((address_space(3))) unsigned int       las_u32;

__device__ __forceinline__ void gload_lds16(const __bf16* g, __bf16* l) {
    __builtin_amdgcn_global_load_lds((gas_u32*)g, (las_u32*)l, 16, 0, 0);
}

// ---------------------------------------------------------------- transpose (f32 -> bf16)
__global__ __launch_bounds__(256) void transpose_bf16(
    const float* __restrict__ in, __bf16* __restrict__ out, int K, int N)
{
    __shared__ float tile[32][33];
    const int k0 = blockIdx.x * 32, n0 = blockIdx.y * 32;
    const int tx = threadIdx.x & 31, ty = threadIdx.x >> 5;
#pragma unroll
    for (int i = 0; i < 32; i += 8)
        tile[ty + i][tx] = in[(size_t)(k0 + ty + i) * N + (n0 + tx)];
    __syncthreads();
#pragma unroll
    for (int i = 0; i < 32; i += 8)
        out[(size_t)(n0 + ty + i) * K + (k0 + tx)] = (__bf16)tile[tx][ty + i];
}

// ---------------------------------------------------------------- transpose V (bf16 -> bf16)
__global__ __launch_bounds__(256) void transpose_v(
    const __bf16* __restrict__ vb, __bf16* __restrict__ vtb)
{
    __shared__ __bf16 tile[32][33];
    const int bh = blockIdx.x;
    const int t0 = blockIdx.y * 32, d0 = blockIdx.z * 32;
    const __bf16* src = vb  + (size_t)bh * T_ * HD_;
    __bf16*       dst = vtb + (size_t)bh * HD_ * T_;
    const int tx = threadIdx.x & 31, ty = threadIdx.x >> 5;
#pragma unroll
    for (int i = 0; i < 32; i += 8)
        tile[ty + i][tx] = src[(size_t)(t0 + ty + i) * HD_ + (d0 + tx)];
    __syncthreads();
#pragma unroll
    for (int i = 0; i < 32; i += 8)
        dst[(size_t)(d0 + ty + i) * T_ + (t0 + tx)] = tile[tx][ty + i];
}

// ---------------------------------------------------------------- group norm (3-stage)
__global__ __launch_bounds__(256) void gn_partial(
    const float* __restrict__ x, float2* __restrict__ part)
{
    const int bg = blockIdx.x, chunk = blockIdx.y;
    const int batch = bg >> 5, g = bg & 31;
    const float* xp = x + (size_t)batch * T_ * H_ + g * 32;
    float s = 0.f, ss = 0.f;
    for (int i = threadIdx.x; i < 128 * 32; i += 256) {
        const int t = chunk * 128 + (i >> 5), c = i & 31;
        const float v = xp[(size_t)t * H_ + c];
        s += v; ss += v * v;
    }
#pragma unroll
    for (int off = 32; off > 0; off >>= 1) {
        s  += __shfl_down(s,  off, 64);
        ss += __shfl_down(ss, off, 64);
    }
    __shared__ float rs[4], rss[4];
    const int wv = threadIdx.x >> 6, lane = threadIdx.x & 63;
    if (lane == 0) { rs[wv] = s; rss[wv] = ss; }
    __syncthreads();
    if (threadIdx.x == 0)
        part[bg * 16 + chunk] =
            make_float2(rs[0] + rs[1] + rs[2] + rs[3],
                        rss[0] + rss[1] + rss[2] + rss[3]);
}

__global__ __launch_bounds__(64) void gn_finalize(
    const float2* __restrict__ part, float2* __restrict__ stats)
{
    const int bg = threadIdx.x;
    float s = 0.f, ss = 0.f;
#pragma unroll
    for (int i = 0; i < 16; ++i) {
        const float2 p = part[bg * 16 + i];
        s += p.x; ss += p.y;
    }
    const float inv = 1.f / (float)(T_ * 32);
    const float mean = s * inv;
    const float var  = ss * inv - mean * mean;
    stats[bg] = make_float2(mean, rsqrtf(var + 1e-5f));
}

__global__ __launch_bounds__(256) void gn_apply(
    const float* __restrict__ x, const float2* __restrict__ stats,
    const float* __restrict__ w, const float* __restrict__ bsc,
    __bf16* __restrict__ out)
{
    const size_t idx = ((size_t)blockIdx.x * 256 + threadIdx.x) * 4;
    const int h = (int)(idx & (H_ - 1));
    const int batch = (int)(idx >> 21);          // T_*H_ = 2^21
    const float2 mr = stats[batch * 32 + (h >> 5)];
    const float4 xv = *(const float4*)(x + idx);
    const float4 wv = *(const float4*)(w + h);
    const float4 bv = *(const float4*)(bsc + h);
    __bf16 o[4];
    o[0] = (__bf16)((xv.x - mr.x) * mr.y * wv.x + bv.x);
    o[1] = (__bf16)((xv.y - mr.x) * mr.y * wv.y + bv.y);
    o[2] = (__bf16)((xv.z - mr.x) * mr.y * wv.z + bv.z);
    o[3] = (__bf16)((xv.w - mr.x) * mr.y * wv.w + bv.w);
    *(uint2*)(out + idx) = *(uint2*)o;
}

// ---------------------------------------------------------------- GEMM core 256x256
// 512 threads = 8 waves (2M x 4N). BK=32, FOUR 32KB buffers (128 KB ring):
// stage tile j+3 while computing j; vmcnt(12) steady (3 tiles of latency
// cover), tail 8/4/0. T2 swizzle + T5 setprio. (R8-verified.)
__device__ __forceinline__ void gemm_core256(
    const __bf16* __restrict__ A, const __bf16* __restrict__ BT,
    int K, int m0, int n0, __bf16* Sb, floatx4 (&acc)[8][4])
{
    const int tid = threadIdx.x, lane = tid & 63, wid = tid >> 6;
    const int quad = lane >> 4, l16 = lane & 15;
    const int wm = (wid >> 2) * 128, wn = (wid & 3) * 64;
    const int r0 = tid >> 2, cbs = tid & 3;
    const int sc  = ((cbs ^ ((r0 >> 1) & 3)) * 8);   // swizzled stage col
    const int xq8 = (quad ^ ((l16 >> 1) & 3)) * 8;   // swizzled read col

    const __bf16* Ag = A  + (size_t)(m0 + r0) * K + sc;
    const __bf16* Bg = BT + (size_t)(n0 + r0) * K + sc;

#define STG256(b, kt)  do {                                                   \
    gload_lds16(Ag + (kt),                  Sb + (b)*16384 + tid*8);          \
    gload_lds16(Ag + (size_t)128*K + (kt),  Sb + (b)*16384 + 4096 + tid*8);   \
    gload_lds16(Bg + (kt),                  Sb + (b)*16384 + 8192 + tid*8);   \
    gload_lds16(Bg + (size_t)128*K + (kt),  Sb + (b)*16384 + 12288 + tid*8); } while (0)

    const int NT = K >> 5;
    STG256(0, 0);
    STG256(1, 32);
    STG256(2, 64);
    int cur = 0;
    for (int j = 0; j < NT; ++j) {
        const int kt = j << 5;
        if (j + 3 < NT) {                      // stage tile j+3, counted wait
            STG256((cur + 3) & 3, kt + 96);
            asm volatile("s_waitcnt vmcnt(12)" ::: "memory");  // tile j landed
        } else if (j + 2 < NT) {
            asm volatile("s_waitcnt vmcnt(8)" ::: "memory");
        } else if (j + 1 < NT) {
            asm volatile("s_waitcnt vmcnt(4)" ::: "memory");
        } else {
            asm volatile("s_waitcnt vmcnt(0)" ::: "memory");
        }
        __builtin_amdgcn_s_barrier();          // all waves: buf[cur] ready
        __builtin_amdgcn_sched_barrier(0);
        const __bf16* Ab = Sb + cur * 16384;
        const __bf16* Bb = Sb + cur * 16384 + 8192;
        bf16x8 af[8], bfg[4];
#pragma unroll
        for (int i = 0; i < 8; ++i)
            af[i]  = *(const bf16x8*)(Ab + (wm + i * 16 + l16) * 32 + xq8);
#pragma unroll
        for (int i = 0; i < 4; ++i)
            bfg[i] = *(const bf16x8*)(Bb + (wn + i * 16 + l16) * 32 + xq8);
        __builtin_amdgcn_s_setprio(1);
#pragma unroll
        for (int mi = 0; mi < 8; ++mi)
#pragma unroll
            for (int ni = 0; ni < 4; ++ni)
                acc[mi][ni] = __builtin_amdgcn_mfma_f32_16x16x32_bf16(
                    af[mi], bfg[ni], acc[mi][ni], 0, 0, 0);
        __builtin_amdgcn_s_setprio(0);
        __builtin_amdgcn_sched_barrier(0);     // keep reads above the barrier
        __builtin_amdgcn_s_barrier();          // reads of buf[cur] done
        __builtin_amdgcn_sched_barrier(0);     // keep next staging below
        cur = (cur + 1) & 3;
    }
#undef STG256
}

#define GEMM256_PROLOGUE(KVAL)                                          \
    __shared__ __align__(16) __bf16 Sb[4 * 16384];  /* 128 KB */        \
    const int m0 = blockIdx.x * 256, n0 = blockIdx.y * 256;             \
    floatx4 acc[8][4];                                                  \
    { floatx4 z = {0.f, 0.f, 0.f, 0.f};                                 \
      for (int i = 0; i < 8; ++i) for (int j = 0; j < 4; ++j) acc[i][j] = z; } \
    gemm_core256(A, BT, (KVAL), m0, n0, Sb, acc);                       \
    const int tid = threadIdx.x, lane = tid & 63, wid = tid >> 6;       \
    const int quad = lane >> 4, l16 = lane & 15;                        \
    const int wm = (wid >> 2) * 128, wn = (wid & 3) * 64;               \
    (void)tid;

// QKV: q (pre-scaled by log2 e), k, v written coalesced [B,NH,T,HD];
// present fp32. v's transposed copy is produced by transpose_v afterwards.
__global__ __launch_bounds__(512) void gemm_qkv(
    const __bf16* __restrict__ A, const __bf16* __restrict__ BT,
    const float* __restrict__ bias, __bf16* __restrict__ qb,
    __bf16* __restrict__ kb, __bf16* __restrict__ vb,
    float* __restrict__ present)
{
    GEMM256_PROLOGUE(H_)
#pragma unroll
    for (int ni = 0; ni < 4; ++ni) {
        const int col = n0 + wn + ni * 16 + l16;
        const float bv = bias[col];
        const int which = col >> 10, c = col & 1023, hh = c >> 6, d = c & 63;
#pragma unroll
        for (int mi = 0; mi < 8; ++mi)
#pragma unroll
            for (int r = 0; r < 4; ++r) {
                const int row = m0 + wm + mi * 16 + quad * 4 + r;
                const int bb = row >> 11, t = row & 2047;
                const float v = acc[mi][ni][r] + bv;
                const size_t idx = (((size_t)bb * NH_ + hh) * T_ + t) * HD_ + d;
                if (which == 0)      qb[idx] = (__bf16)(v * 1.4426950408889634f);
                else if (which == 1) { kb[idx] = (__bf16)v; present[idx] = v; }
                else { vb[idx] = (__bf16)v;
                       present[(size_t)B_ * NH_ * T_ * HD_ + idx] = v; }
            }
    }
}

// gelu via sigmoid identity: 0.5v(1+tanh(u)) = v * sigmoid(2u)
__global__ __launch_bounds__(512) void gemm_gelu(
    const __bf16* __restrict__ A, const __bf16* __restrict__ BT,
    const float* __restrict__ bias, __bf16* __restrict__ out)
{
    GEMM256_PROLOGUE(H_)
#pragma unroll
    for (int ni = 0; ni < 4; ++ni) {
        const int col = n0 + wn + ni * 16 + l16;
        const float bv = bias[col];
#pragma unroll
        for (int mi = 0; mi < 8; ++mi)
#pragma unroll
            for (int r = 0; r < 4; ++r) {
                const int row = m0 + wm + mi * 16 + quad * 4 + r;
                const float v = acc[mi][ni][r] + bv;
                const float e = exp2f(-2.3022082f * (v + 0.044715f * v * v * v));
                float rcp;
                asm("v_rcp_f32 %0, %1" : "=v"(rcp) : "v"(1.f + e));
                out[(size_t)row * (4 * H_) + col] = (__bf16)(v * rcp);
            }
    }
}

// ---------------------------------------------------------------- GEMM 128x64 + resid
// R8-measured-best (66 us @ K=4096): BK=64 THREE-buffer ring (72 KB LDS,
// 2 blocks/CU at the 512-block grid -> 8 waves/CU): stage tile j+2 into slot
// (j+2)%3; vmcnt(12) steady; tail 6/0. T2 swizzle. (R10's 128x128 variant
// regressed: its 256-block grid capped residency at 1 block/CU.)
__global__ __launch_bounds__(256) void gemm_resid_n64(
    const __bf16* __restrict__ A, const __bf16* __restrict__ BT,
    const float* __restrict__ bias, const float* __restrict__ resid,
    float* __restrict__ out, int K, int N)
{
    __shared__ __align__(16) __bf16 As[3 * 8192], Bs[3 * 4096];
    const int m0 = blockIdx.x * 128, n0 = blockIdx.y * 64;
    const int tid  = threadIdx.x;
    const int lane = tid & 63, wv = tid >> 6;
    const int quad = lane >> 4, l16 = lane & 15;
    const int wm = (wv >> 1) * 64, wn = (wv & 1) * 32;
    const int r0 = tid >> 2;
    const int scs = (((tid & 3) ^ ((r0 >> 1) & 3)) * 8);
    const int xq8 = (quad ^ ((l16 >> 1) & 3)) * 8;

    floatx4 acc[4][2];
    { floatx4 z = {0.f, 0.f, 0.f, 0.f};
#pragma unroll
      for (int i = 0; i < 4; ++i) { acc[i][0] = z; acc[i][1] = z; } }

    const __bf16* Ag = A  + (size_t)(m0 + r0) * K + scs;
    const __bf16* Bg = BT + (size_t)(n0 + r0) * K + scs;

#define STGR(b, kt)  do {                                                     \
    _Pragma("unroll")                                                         \
    for (int s = 0; s < 2; ++s) {                                             \
        gload_lds16(Ag + (kt) + s * 32,                  As + (b)*8192 + s*4096 + tid*8);        \
        gload_lds16(Ag + (size_t)64 * K + (kt) + s * 32, As + (b)*8192 + s*4096 + 2048 + tid*8); \
        gload_lds16(Bg + (kt) + s * 32,                  Bs + (b)*4096 + s*2048 + tid*8);        \
    } } while (0)

    const int NT = K >> 6;
    STGR(0, 0);
    STGR(1, 64);
    int cur = 0;
    for (int j = 0; j < NT; ++j) {
        const int kt = j << 6;
        if (j + 2 < NT) {
            int nb = cur + 2; if (nb >= 3) nb -= 3;
            STGR(nb, kt + 128);
            asm volatile("s_waitcnt vmcnt(12)" ::: "memory");  // tile j landed
        } else if (j + 1 < NT) {
            asm volatile("s_waitcnt vmcnt(6)" ::: "memory");
        } else {
            asm volatile("s_waitcnt vmcnt(0)" ::: "memory");
        }
        __builtin_amdgcn_s_barrier();
        __builtin_amdgcn_sched_barrier(0);
        const __bf16* Ab = As + cur * 8192;
        const __bf16* Bb = Bs + cur * 4096;
#pragma unroll
        for (int kk = 0; kk < 2; ++kk) {
            bf16x8 af[4], bfg[2];
#pragma unroll
            for (int i = 0; i < 4; ++i)
                af[i]  = *(const bf16x8*)(Ab + kk * 4096 + (wm + i * 16 + l16) * 32 + xq8);
#pragma unroll
            for (int i = 0; i < 2; ++i)
                bfg[i] = *(const bf16x8*)(Bb + kk * 2048 + (wn + i * 16 + l16) * 32 + xq8);
#pragma unroll
            for (int mi = 0; mi < 4; ++mi)
#pragma unroll
                for (int ni = 0; ni < 2; ++ni)
                    acc[mi][ni] = __builtin_amdgcn_mfma_f32_16x16x32_bf16(
                        af[mi], bfg[ni], acc[mi][ni], 0, 0, 0);
        }
        __builtin_amdgcn_sched_barrier(0);
        __builtin_amdgcn_s_barrier();
        __builtin_amdgcn_sched_barrier(0);
        cur = cur + 1; if (cur >= 3) cur = 0;
    }
#undef STGR

#pragma unroll
    for (int ni = 0; ni < 2; ++ni) {
        const int col = n0 + wn + ni * 16 + l16;
        const float bv = bias[col];
#pragma unroll
        for (int mi = 0; mi < 4; ++mi)
#pragma unroll
            for (int r = 0; r < 4; ++r) {
                const int row = m0 + wm + mi * 16 + quad * 4 + r;
                const size_t idx = (size_t)row * N + col;
                out[idx] = acc[mi][ni][r] + bv + resid[idx];
            }
    }
}

// ---------------------------------------------------------------- attention v3
// v2 + lane-local defer-max: the cross-lane row-max shuffle reduce runs ONLY
// when the rescale triggers (rare). Trigger condition is exactly equivalent:
// any row's true max > m+8  <=>  any lane's local max > m+8 (__any = OR).
__global__ __launch_bounds__(256) void attn_kernel(
    const __bf16* __restrict__ qb, const __bf16* __restrict__ kb,
    const __bf16* __restrict__ vtb, __bf16* __restrict__ aout)
{
    const int bh = blockIdx.x;
    const int sp = 31 - blockIdx.y;          // LPT: longest blocks dispatched first
    const int bb = bh >> 4, hh = bh & 15;
    const __bf16* Q  = qb  + (size_t)bh * T_ * HD_;
    const __bf16* Kp = kb  + (size_t)bh * T_ * HD_;
    const __bf16* VT = vtb + (size_t)bh * HD_ * T_;
    __shared__ __align__(16) __bf16 Qs[2 * 2048];
    __shared__ __align__(16) __bf16 Ks[2][2 * 2048];
    __shared__ __align__(16) __bf16 Vs[2][2 * 2048];
    __shared__ __align__(16) __bf16 Ps[64 * PS_];

    const int tid = threadIdx.x, lane = tid & 63, wv = tid >> 6;
    const int quad = lane >> 4, l16 = lane & 15;
    const int sr = tid >> 2;                              // staging row 0..63
    const int scs = (((tid & 3) ^ ((sr >> 1) & 3)) * 8);  // swizzled stage col
    const int xq8 = (quad ^ ((l16 >> 1) & 3)) * 8;        // swizzled read col

    const int q0 = sp * 64, nkt = sp + 1;

    // prologue: stage Q + K/V tile 0, drain, hoist Q to regs
#pragma unroll
    for (int s = 0; s < 2; ++s) {
        gload_lds16(Q  + (size_t)(q0 + sr) * HD_ + s * 32 + scs, Qs + s * 2048 + tid * 8);
        gload_lds16(Kp + (size_t)sr * HD_ + s * 32 + scs, &Ks[0][s * 2048 + tid * 8]);
        gload_lds16(VT + (size_t)sr * T_  + s * 32 + scs, &Vs[0][s * 2048 + tid * 8]);
    }
    asm volatile("s_waitcnt vmcnt(0)" ::: "memory");
    __builtin_amdgcn_s_barrier();
    __builtin_amdgcn_sched_barrier(0);

    bf16x8 aq[2];
#pragma unroll
    for (int kk = 0; kk < 2; ++kk)
        aq[kk] = *(const bf16x8*)(Qs + kk * 2048 + (wv * 16 + l16) * 32 + xq8);

    float m_i[4], l_p[4];
    floatx4 Ov[4];
    { floatx4 z = {0.f, 0.f, 0.f, 0.f};
#pragma unroll
      for (int i = 0; i < 4; ++i) { Ov[i] = z; m_i[i] = -1e30f; l_p[i] = 0.f; } }

    int cur = 0;
    for (int kt = 0; kt < nkt; ++kt) {
        if (kt + 1 < nkt) {
            const int kn = (kt + 1) * 64;
#pragma unroll
            for (int s = 0; s < 2; ++s) {
                gload_lds16(Kp + (size_t)(kn + sr) * HD_ + s * 32 + scs,
                            &Ks[cur ^ 1][s * 2048 + tid * 8]);
                gload_lds16(VT + (size_t)sr * T_ + kn + s * 32 + scs,
                            &Vs[cur ^ 1][s * 2048 + tid * 8]);
            }
            asm volatile("s_waitcnt vmcnt(4)" ::: "memory");   // tile kt landed
        } else {
            asm volatile("s_waitcnt vmcnt(0)" ::: "memory");
        }
        __builtin_amdgcn_s_barrier();          // all waves: buf[cur] ready
        __builtin_amdgcn_sched_barrier(0);

        const __bf16* Kc = Ks[cur];
        const __bf16* Vc = Vs[cur];

        // S = Q K^T (log2-domain scores)
        floatx4 sacc[4];
        { floatx4 z = {0.f, 0.f, 0.f, 0.f};
#pragma unroll
          for (int i = 0; i < 4; ++i) sacc[i] = z; }
#pragma unroll
        for (int kk = 0; kk < 2; ++kk)
#pragma unroll
            for (int ni = 0; ni < 4; ++ni) {
                const bf16x8 bk = *(const bf16x8*)(Kc + kk * 2048 + (ni * 16 + l16) * 32 + xq8);
                sacc[ni] = __builtin_amdgcn_mfma_f32_16x16x32_bf16(aq[kk], bk, sacc[ni], 0, 0, 0);
            }
        if (kt == sp) {    // diagonal tile: causal mask (local coords)
#pragma unroll
            for (int ni = 0; ni < 4; ++ni) {
                const int keyL = ni * 16 + l16;
#pragma unroll
                for (int r = 0; r < 4; ++r)
                    if (keyL > quad * 4 + r + wv * 16) sacc[ni][r] = -1e30f;
            }
        }
        // defer-max, lane-local trigger: shuffles only when rescale needed
        float rml[4];
#pragma unroll
        for (int r = 0; r < 4; ++r)
            rml[r] = fmaxf(fmaxf(sacc[0][r], sacc[1][r]),
                           fmaxf(sacc[2][r], sacc[3][r]));
        float need = rml[0] - m_i[0];
#pragma unroll
        for (int r = 1; r < 4; ++r) need = fmaxf(need, rml[r] - m_i[r]);
        if (__any(need > 8.f)) {               // rare: exact row max + rescale
#pragma unroll
            for (int off = 1; off < 16; off <<= 1)
#pragma unroll
                for (int r = 0; r < 4; ++r)
                    rml[r] = fmaxf(rml[r], __shfl_xor(rml[r], off, 64));
#pragma unroll
            for (int r = 0; r < 4; ++r) {
                const float mn = fmaxf(m_i[r], rml[r]);
                const float al = exp2f(m_i[r] - mn);
                m_i[r] = mn;
                l_p[r] *= al;
#pragma unroll
                for (int ni = 0; ni < 4; ++ni) Ov[ni][r] *= al;
            }
        }
#pragma unroll
        for (int ni = 0; ni < 4; ++ni)
#pragma unroll
            for (int r = 0; r < 4; ++r) {
                const float pe = exp2f(sacc[ni][r] - m_i[r]);
                sacc[ni][r] = pe;
                l_p[r] += pe;                  // lane-partial; reduced at end
            }
        // P: C-layout -> A-layout via wave-private LDS rows (stride 72)
#pragma unroll
        for (int ni = 0; ni < 4; ++ni)
#pragma unroll
            for (int r = 0; r < 4; ++r)
                Ps[(wv * 16 + quad * 4 + r) * PS_ + ni * 16 + l16] = (__bf16)sacc[ni][r];
        // O += P V
#pragma unroll
        for (int kk = 0; kk < 2; ++kk) {
            const bf16x8 ap = *(const bf16x8*)(Ps + (wv * 16 + l16) * PS_ + kk * 32 + quad * 8);
#pragma unroll
            for (int ni = 0; ni < 4; ++ni) {
                const bf16x8 bv2 = *(const bf16x8*)(Vc + kk * 2048 + (ni * 16 + l16) * 32 + xq8);
                Ov[ni] = __builtin_amdgcn_mfma_f32_16x16x32_bf16(ap, bv2, Ov[ni], 0, 0, 0);
            }
        }
        __builtin_amdgcn_sched_barrier(0);     // keep reads above the barrier
        __builtin_amdgcn_s_barrier();          // reads of buf[cur] done
        __builtin_amdgcn_sched_barrier(0);     // keep next staging below
        cur ^= 1;
    }
    // epilogue: reduce lane-partial l across the 16 key-lanes, then store
#pragma unroll
    for (int off = 1; off < 16; off <<= 1)
#pragma unroll
        for (int r = 0; r < 4; ++r)
            l_p[r] += __shfl_xor(l_p[r], off, 64);
#pragma unroll
    for (int ni = 0; ni < 4; ++ni)
#pragma unroll
        for (int r = 0; r < 4; ++r) {
            const int t = q0 + wv * 16 + quad * 4 + r;
            aout[((size_t)(bb * T_ + t)) * H_ + hh * HD_ + ni * 16 + l16] =
                (__bf16)(Ov[ni][r] / l_p[r]);
        }
}

// ---------------------------------------------------------------- launch
extern "C" void kernel_launch(void* const* d_in, const int* in_sizes, int n_in,
                              void* d_out, int out_size, void* d_ws, size_t ws_size,
                              hipStream_t stream)
{
    (void)in_sizes; (void)n_in; (void)out_size; (void)ws_size;
    const float* x       = (const float*)d_in[0];
    const float* w_attn  = (const float*)d_in[1];
    const float* b_attn  = (const float*)d_in[2];
    const float* w_aproj = (const float*)d_in[3];
    const float* b_aproj = (const float*)d_in[4];
    const float* ln1_w   = (const float*)d_in[5];
    const float* ln1_b   = (const float*)d_in[6];
    const float* ln2_w   = (const float*)d_in[7];
    const float* ln2_b   = (const float*)d_in[8];
    const float* w_fc    = (const float*)d_in[9];
    const float* b_fc    = (const float*)d_in[10];
    const float* w_mproj = (const float*)d_in[11];
    const float* b_mproj = (const float*)d_in[12];
    float* out = (float*)d_out;
    float* present = out + (size_t)M_ * H_;

    char* wp = (char*)d_ws;
    auto alloc = [&](size_t bytes) {
        void* p = (void*)wp; wp += (bytes + 255) & ~(size_t)255; return p;
    };
    __bf16* A1       = (__bf16*)alloc((size_t)M_ * H_ * 2);
    __bf16* A2       = (__bf16*)alloc((size_t)M_ * H_ * 2);
    __bf16* WattnT   = (__bf16*)alloc((size_t)3 * H_ * H_ * 2);
    __bf16* WaprojT  = (__bf16*)alloc((size_t)H_ * H_ * 2);
    __bf16* WfcT     = (__bf16*)alloc((size_t)4 * H_ * H_ * 2);
    __bf16* WmprojT  = (__bf16*)alloc((size_t)4 * H_ * H_ * 2);
    __bf16* qb       = (__bf16*)alloc((size_t)M_ * H_ * 2);
    __bf16* kb       = (__bf16*)alloc((size_t)M_ * H_ * 2);
    __bf16* vb       = (__bf16*)alloc((size_t)M_ * H_ * 2);
    __bf16* vtb      = (__bf16*)alloc((size_t)M_ * H_ * 2);
    __bf16* attn_out = (__bf16*)alloc((size_t)M_ * H_ * 2);
    float*  x2       = (float*) alloc((size_t)M_ * H_ * 4);
    __bf16* Hbuf     = (__bf16*)alloc((size_t)M_ * 4 * H_ * 2);
    float2* gn_part  = (float2*)alloc(64 * 16 * sizeof(float2));
    float2* gn_stats = (float2*)alloc(64 * sizeof(float2));

    transpose_bf16<<<dim3(H_/32, 3*H_/32), 256, 0, stream>>>(w_attn,  WattnT,  H_,   3*H_);
    transpose_bf16<<<dim3(H_/32, H_/32),   256, 0, stream>>>(w_aproj, WaprojT, H_,   H_);
    transpose_bf16<<<dim3(H_/32, 4*H_/32), 256, 0, stream>>>(w_fc,    WfcT,    H_,   4*H_);
    transpose_bf16<<<dim3(4*H_/32, H_/32), 256, 0, stream>>>(w_mproj, WmprojT, 4*H_, H_);

    gn_partial <<<dim3(64, 16), 256, 0, stream>>>(x, gn_part);
    gn_finalize<<<1, 64, 0, stream>>>(gn_part, gn_stats);
    gn_apply   <<<M_*H_/1024, 256, 0, stream>>>(x, gn_stats, ln1_w, ln1_b, A1);

    gemm_qkv<<<dim3(M_/256, 3*H_/256), 512, 0, stream>>>(A1, WattnT, b_attn,
                                                         qb, kb, vb, present);
    transpose_v<<<dim3(B_*NH_, T_/32, HD_/32), 256, 0, stream>>>(vb, vtb);
    attn_kernel<<<dim3(32, 32), 256, 0, stream>>>(qb, kb, vtb, attn_out);
    gemm_resid_n64<<<dim3(M_/128, H_/64), 256, 0, stream>>>(attn_out, WaprojT, b_aproj,
                                                            x, x2, H_, H_);

    gn_partial <<<dim3(64, 16), 256, 0, stream>>>(x2, gn_part);
    gn_finalize<<<1, 64, 0, stream>>>(gn_part, gn_stats);
    gn_apply   <<<M_*H_/1024, 256, 0, stream>>>(x2, gn_stats, ln2_w, ln2_b, A2);

    gemm_gelu<<<dim3(M_/256, 4*H_/256), 512, 0, stream>>>(A2, WfcT, b_fc, Hbuf);
    gemm_resid_n64<<<dim3(M_/128, H_/64), 256, 0, stream>>>(Hbuf, WmprojT, b_mproj,
                                                            x2, out, 4*H_, H_);
}

// Round 12
// 390.822 us; speedup vs baseline: 1.0718x; 1.0258x over previous
//
#include <hip/hip_runtime.h>

#define B_  2
#define T_  2048
#define H_  1024
#define NH_ 16
#define HD_ 64
#define M_  (B_*T_)   // 4096 rows
#define PS_ 72        // P-matrix LDS row stride (64 data + 8 pad)

typedef __bf16 bf16x8 __attribute__((ext_vector_type(8)));
typedef float  floatx4 __attribute__((ext_vector_type(4)));

typedef __attribute__((address_space(1))) const unsigned int gas_u32;
typedef __attribute__((address_space(3))) unsigned int       las_u32;

__device__ __forceinline__ void gload_lds16(const __bf16* g, __bf16* l) {
    __builtin_amdgcn_global_load_lds((gas_u32*)g, (las_u32*)l, 16, 0, 0);
}

// ---------------------------------------------------------------- transpose (f32 -> bf16)
__global__ __launch_bounds__(256) void transpose_bf16(
    const float* __restrict__ in, __bf16* __restrict__ out, int K, int N)
{
    __shared__ float tile[32][33];
    const int k0 = blockIdx.x * 32, n0 = blockIdx.y * 32;
    const int tx = threadIdx.x & 31, ty = threadIdx.x >> 5;
#pragma unroll
    for (int i = 0; i < 32; i += 8)
        tile[ty + i][tx] = in[(size_t)(k0 + ty + i) * N + (n0 + tx)];
    __syncthreads();
#pragma unroll
    for (int i = 0; i < 32; i += 8)
        out[(size_t)(n0 + ty + i) * K + (k0 + tx)] = (__bf16)tile[tx][ty + i];
}

// ---------------------------------------------------------------- transpose V (bf16 -> bf16)
__global__ __launch_bounds__(256) void transpose_v(
    const __bf16* __restrict__ vb, __bf16* __restrict__ vtb)
{
    __shared__ __bf16 tile[32][33];
    const int bh = blockIdx.x;
    const int t0 = blockIdx.y * 32, d0 = blockIdx.z * 32;
    const __bf16* src = vb  + (size_t)bh * T_ * HD_;
    __bf16*       dst = vtb + (size_t)bh * HD_ * T_;
    const int tx = threadIdx.x & 31, ty = threadIdx.x >> 5;
#pragma unroll
    for (int i = 0; i < 32; i += 8)
        tile[ty + i][tx] = src[(size_t)(t0 + ty + i) * HD_ + (d0 + tx)];
    __syncthreads();
#pragma unroll
    for (int i = 0; i < 32; i += 8)
        dst[(size_t)(d0 + ty + i) * T_ + (t0 + tx)] = tile[tx][ty + i];
}

// ---------------------------------------------------------------- group norm
// gn_partial: only needed for ln1 (input x). ln2's partials are produced by
// the aproj gemm_resid_n64 epilogue (same [bg][16] layout, same granularity).
__global__ __launch_bounds__(256) void gn_partial(
    const float* __restrict__ x, float2* __restrict__ part)
{
    const int bg = blockIdx.x, chunk = blockIdx.y;
    const int batch = bg >> 5, g = bg & 31;
    const float* xp = x + (size_t)batch * T_ * H_ + g * 32;
    float s = 0.f, ss = 0.f;
    for (int i = threadIdx.x; i < 128 * 32; i += 256) {
        const int t = chunk * 128 + (i >> 5), c = i & 31;
        const float v = xp[(size_t)t * H_ + c];
        s += v; ss += v * v;
    }
#pragma unroll
    for (int off = 32; off > 0; off >>= 1) {
        s  += __shfl_down(s,  off, 64);
        ss += __shfl_down(ss, off, 64);
    }
    __shared__ float rs[4], rss[4];
    const int wv = threadIdx.x >> 6, lane = threadIdx.x & 63;
    if (lane == 0) { rs[wv] = s; rss[wv] = ss; }
    __syncthreads();
    if (threadIdx.x == 0)
        part[bg * 16 + chunk] =
            make_float2(rs[0] + rs[1] + rs[2] + rs[3],
                        rss[0] + rss[1] + rss[2] + rss[3]);
}

// gn_apply with fused finalize: threads 0-31 reduce the 16 partials of their
// group (L2-hot, 8 KB) into LDS; no separate gn_finalize launch, no stats buf.
__global__ __launch_bounds__(256) void gn_apply(
    const float* __restrict__ x, const float2* __restrict__ part,
    const float* __restrict__ w, const float* __restrict__ bsc,
    __bf16* __restrict__ out)
{
    __shared__ float2 st[32];
    const size_t base = (size_t)blockIdx.x * 1024;
    const int batch = (int)(base >> 21);         // T_*H_ = 2^21
    if (threadIdx.x < 32) {
        const float2* p = part + ((size_t)batch * 32 + threadIdx.x) * 16;
        float s = 0.f, ss = 0.f;
#pragma unroll
        for (int i = 0; i < 16; ++i) { s += p[i].x; ss += p[i].y; }
        const float inv = 1.f / (float)(T_ * 32);
        const float mean = s * inv;
        st[threadIdx.x] = make_float2(mean, rsqrtf(ss * inv - mean * mean + 1e-5f));
    }
    __syncthreads();
    const size_t idx = base + (size_t)threadIdx.x * 4;
    const int h = (int)(idx & (H_ - 1));
    const float2 mr = st[h >> 5];
    const float4 xv = *(const float4*)(x + idx);
    const float4 wv = *(const float4*)(w + h);
    const float4 bv = *(const float4*)(bsc + h);
    __bf16 o[4];
    o[0] = (__bf16)((xv.x - mr.x) * mr.y * wv.x + bv.x);
    o[1] = (__bf16)((xv.y - mr.x) * mr.y * wv.y + bv.y);
    o[2] = (__bf16)((xv.z - mr.x) * mr.y * wv.z + bv.z);
    o[3] = (__bf16)((xv.w - mr.x) * mr.y * wv.w + bv.w);
    *(uint2*)(out + idx) = *(uint2*)o;
}

// ---------------------------------------------------------------- GEMM core 256x256
// 512 threads = 8 waves (2M x 4N). BK=32, FOUR 32KB buffers (128 KB ring):
// stage tile j+3 while computing j; vmcnt(12) steady (3 tiles of latency
// cover), tail 8/4/0. T2 swizzle + T5 setprio. (R8-verified.)
__device__ __forceinline__ void gemm_core256(
    const __bf16* __restrict__ A, const __bf16* __restrict__ BT,
    int K, int m0, int n0, __bf16* Sb, floatx4 (&acc)[8][4])
{
    const int tid = threadIdx.x, lane = tid & 63, wid = tid >> 6;
    const int quad = lane >> 4, l16 = lane & 15;
    const int wm = (wid >> 2) * 128, wn = (wid & 3) * 64;
    const int r0 = tid >> 2, cbs = tid & 3;
    const int sc  = ((cbs ^ ((r0 >> 1) & 3)) * 8);   // swizzled stage col
    const int xq8 = (quad ^ ((l16 >> 1) & 3)) * 8;   // swizzled read col

    const __bf16* Ag = A  + (size_t)(m0 + r0) * K + sc;
    const __bf16* Bg = BT + (size_t)(n0 + r0) * K + sc;

#define STG256(b, kt)  do {                                                   \
    gload_lds16(Ag + (kt),                  Sb + (b)*16384 + tid*8);          \
    gload_lds16(Ag + (size_t)128*K + (kt),  Sb + (b)*16384 + 4096 + tid*8);   \
    gload_lds16(Bg + (kt),                  Sb + (b)*16384 + 8192 + tid*8);   \
    gload_lds16(Bg + (size_t)128*K + (kt),  Sb + (b)*16384 + 12288 + tid*8); } while (0)

    const int NT = K >> 5;
    STG256(0, 0);
    STG256(1, 32);
    STG256(2, 64);
    int cur = 0;
    for (int j = 0; j < NT; ++j) {
        const int kt = j << 5;
        if (j + 3 < NT) {                      // stage tile j+3, counted wait
            STG256((cur + 3) & 3, kt + 96);
            asm volatile("s_waitcnt vmcnt(12)" ::: "memory");  // tile j landed
        } else if (j + 2 < NT) {
            asm volatile("s_waitcnt vmcnt(8)" ::: "memory");
        } else if (j + 1 < NT) {
            asm volatile("s_waitcnt vmcnt(4)" ::: "memory");
        } else {
            asm volatile("s_waitcnt vmcnt(0)" ::: "memory");
        }
        __builtin_amdgcn_s_barrier();          // all waves: buf[cur] ready
        __builtin_amdgcn_sched_barrier(0);
        const __bf16* Ab = Sb + cur * 16384;
        const __bf16* Bb = Sb + cur * 16384 + 8192;
        bf16x8 af[8], bfg[4];
#pragma unroll
        for (int i = 0; i < 8; ++i)
            af[i]  = *(const bf16x8*)(Ab + (wm + i * 16 + l16) * 32 + xq8);
#pragma unroll
        for (int i = 0; i < 4; ++i)
            bfg[i] = *(const bf16x8*)(Bb + (wn + i * 16 + l16) * 32 + xq8);
        __builtin_amdgcn_s_setprio(1);
#pragma unroll
        for (int mi = 0; mi < 8; ++mi)
#pragma unroll
            for (int ni = 0; ni < 4; ++ni)
                acc[mi][ni] = __builtin_amdgcn_mfma_f32_16x16x32_bf16(
                    af[mi], bfg[ni], acc[mi][ni], 0, 0, 0);
        __builtin_amdgcn_s_setprio(0);
        __builtin_amdgcn_sched_barrier(0);     // keep reads above the barrier
        __builtin_amdgcn_s_barrier();          // reads of buf[cur] done
        __builtin_amdgcn_sched_barrier(0);     // keep next staging below
        cur = (cur + 1) & 3;
    }
#undef STG256
}

#define GEMM256_PROLOGUE(KVAL)                                          \
    __shared__ __align__(16) __bf16 Sb[4 * 16384];  /* 128 KB */        \
    const int m0 = blockIdx.x * 256, n0 = blockIdx.y * 256;             \
    floatx4 acc[8][4];                                                  \
    { floatx4 z = {0.f, 0.f, 0.f, 0.f};                                 \
      for (int i = 0; i < 8; ++i) for (int j = 0; j < 4; ++j) acc[i][j] = z; } \
    gemm_core256(A, BT, (KVAL), m0, n0, Sb, acc);                       \
    const int tid = threadIdx.x, lane = tid & 63, wid = tid >> 6;       \
    const int quad = lane >> 4, l16 = lane & 15;                        \
    const int wm = (wid >> 2) * 128, wn = (wid & 3) * 64;               \
    (void)tid;

// QKV: q (pre-scaled by log2 e), k, v written coalesced [B,NH,T,HD];
// present fp32. v's transposed copy is produced by transpose_v afterwards.
__global__ __launch_bounds__(512) void gemm_qkv(
    const __bf16* __restrict__ A, const __bf16* __restrict__ BT,
    const float* __restrict__ bias, __bf16* __restrict__ qb,
    __bf16* __restrict__ kb, __bf16* __restrict__ vb,
    float* __restrict__ present)
{
    GEMM256_PROLOGUE(H_)
#pragma unroll
    for (int ni = 0; ni < 4; ++ni) {
        const int col = n0 + wn + ni * 16 + l16;
        const float bv = bias[col];
        const int which = col >> 10, c = col & 1023, hh = c >> 6, d = c & 63;
#pragma unroll
        for (int mi = 0; mi < 8; ++mi)
#pragma unroll
            for (int r = 0; r < 4; ++r) {
                const int row = m0 + wm + mi * 16 + quad * 4 + r;
                const int bb = row >> 11, t = row & 2047;
                const float v = acc[mi][ni][r] + bv;
                const size_t idx = (((size_t)bb * NH_ + hh) * T_ + t) * HD_ + d;
                if (which == 0)      qb[idx] = (__bf16)(v * 1.4426950408889634f);
                else if (which == 1) { kb[idx] = (__bf16)v; present[idx] = v; }
                else { vb[idx] = (__bf16)v;
                       present[(size_t)B_ * NH_ * T_ * HD_ + idx] = v; }
            }
    }
}

// gelu via sigmoid identity: 0.5v(1+tanh(u)) = v * sigmoid(2u)
__global__ __launch_bounds__(512) void gemm_gelu(
    const __bf16* __restrict__ A, const __bf16* __restrict__ BT,
    const float* __restrict__ bias, __bf16* __restrict__ out)
{
    GEMM256_PROLOGUE(H_)
#pragma unroll
    for (int ni = 0; ni < 4; ++ni) {
        const int col = n0 + wn + ni * 16 + l16;
        const float bv = bias[col];
#pragma unroll
        for (int mi = 0; mi < 8; ++mi)
#pragma unroll
            for (int r = 0; r < 4; ++r) {
                const int row = m0 + wm + mi * 16 + quad * 4 + r;
                const float v = acc[mi][ni][r] + bv;
                const float e = exp2f(-2.3022082f * (v + 0.044715f * v * v * v));
                float rcp;
                asm("v_rcp_f32 %0, %1" : "=v"(rcp) : "v"(1.f + e));
                out[(size_t)row * (4 * H_) + col] = (__bf16)(v * rcp);
            }
    }
}

// ---------------------------------------------------------------- GEMM 128x64 + resid
// R8-measured-best: BK=64 THREE-buffer ring (72 KB, 2 blocks/CU): stage tile
// j+2; vmcnt(12) steady; tail 6/0. T2 swizzle.
// NEW: optional fused GroupNorm partials (gnp != nullptr, aproj call only):
// each wave's 32 output values all belong to group (n0>>5)+(wv&1), so one
// 64-lane shuffle reduce + LDS combine emits gn_part[(batch*32+g)*16+mblk]
// in exactly gn_partial's layout/granularity (128 rows x 32 cols).
__global__ __launch_bounds__(256) void gemm_resid_n64(
    const __bf16* __restrict__ A, const __bf16* __restrict__ BT,
    const float* __restrict__ bias, const float* __restrict__ resid,
    float* __restrict__ out, float2* __restrict__ gnp, int K, int N)
{
    __shared__ __align__(16) __bf16 As[3 * 8192], Bs[3 * 4096];
    const int m0 = blockIdx.x * 128, n0 = blockIdx.y * 64;
    const int tid  = threadIdx.x;
    const int lane = tid & 63, wv = tid >> 6;
    const int quad = lane >> 4, l16 = lane & 15;
    const int wm = (wv >> 1) * 64, wn = (wv & 1) * 32;
    const int r0 = tid >> 2;
    const int scs = (((tid & 3) ^ ((r0 >> 1) & 3)) * 8);
    const int xq8 = (quad ^ ((l16 >> 1) & 3)) * 8;

    floatx4 acc[4][2];
    { floatx4 z = {0.f, 0.f, 0.f, 0.f};
#pragma unroll
      for (int i = 0; i < 4; ++i) { acc[i][0] = z; acc[i][1] = z; } }

    const __bf16* Ag = A  + (size_t)(m0 + r0) * K + scs;
    const __bf16* Bg = BT + (size_t)(n0 + r0) * K + scs;

#define STGR(b, kt)  do {                                                     \
    _Pragma("unroll")                                                         \
    for (int s = 0; s < 2; ++s) {                                             \
        gload_lds16(Ag + (kt) + s * 32,                  As + (b)*8192 + s*4096 + tid*8);        \
        gload_lds16(Ag + (size_t)64 * K + (kt) + s * 32, As + (b)*8192 + s*4096 + 2048 + tid*8); \
        gload_lds16(Bg + (kt) + s * 32,                  Bs + (b)*4096 + s*2048 + tid*8);        \
    } } while (0)

    const int NT = K >> 6;
    STGR(0, 0);
    STGR(1, 64);
    int cur = 0;
    for (int j = 0; j < NT; ++j) {
        const int kt = j << 6;
        if (j + 2 < NT) {
            int nb = cur + 2; if (nb >= 3) nb -= 3;
            STGR(nb, kt + 128);
            asm volatile("s_waitcnt vmcnt(12)" ::: "memory");  // tile j landed
        } else if (j + 1 < NT) {
            asm volatile("s_waitcnt vmcnt(6)" ::: "memory");
        } else {
            asm volatile("s_waitcnt vmcnt(0)" ::: "memory");
        }
        __builtin_amdgcn_s_barrier();
        __builtin_amdgcn_sched_barrier(0);
        const __bf16* Ab = As + cur * 8192;
        const __bf16* Bb = Bs + cur * 4096;
#pragma unroll
        for (int kk = 0; kk < 2; ++kk) {
            bf16x8 af[4], bfg[2];
#pragma unroll
            for (int i = 0; i < 4; ++i)
                af[i]  = *(const bf16x8*)(Ab + kk * 4096 + (wm + i * 16 + l16) * 32 + xq8);
#pragma unroll
            for (int i = 0; i < 2; ++i)
                bfg[i] = *(const bf16x8*)(Bb + kk * 2048 + (wn + i * 16 + l16) * 32 + xq8);
#pragma unroll
            for (int mi = 0; mi < 4; ++mi)
#pragma unroll
                for (int ni = 0; ni < 2; ++ni)
                    acc[mi][ni] = __builtin_amdgcn_mfma_f32_16x16x32_bf16(
                        af[mi], bfg[ni], acc[mi][ni], 0, 0, 0);
        }
        __builtin_amdgcn_sched_barrier(0);
        __builtin_amdgcn_s_barrier();
        __builtin_amdgcn_sched_barrier(0);
        cur = cur + 1; if (cur >= 3) cur = 0;
    }
#undef STGR

    float s = 0.f, ss = 0.f;
#pragma unroll
    for (int ni = 0; ni < 2; ++ni) {
        const int col = n0 + wn + ni * 16 + l16;
        const float bv = bias[col];
#pragma unroll
        for (int mi = 0; mi < 4; ++mi)
#pragma unroll
            for (int r = 0; r < 4; ++r) {
                const int row = m0 + wm + mi * 16 + quad * 4 + r;
                const size_t idx = (size_t)row * N + col;
                const float v = acc[mi][ni][r] + bv + resid[idx];
                out[idx] = v;
                s += v; ss += v * v;
            }
    }
    if (gnp) {                                 // fused GN partials (aproj only)
        __shared__ float pr[4][2];
#pragma unroll
        for (int off = 32; off > 0; off >>= 1) {
            s  += __shfl_down(s,  off, 64);
            ss += __shfl_down(ss, off, 64);
        }
        if (lane == 0) { pr[wv][0] = s; pr[wv][1] = ss; }
        __syncthreads();
        if (tid < 2) {                         // waves {0,2}->g, {1,3}->g+1
            const float S  = pr[tid][0] + pr[tid + 2][0];
            const float SS = pr[tid][1] + pr[tid + 2][1];
            const int batch = m0 >> 11;        // rows per batch = 2048
            const int mblk  = (m0 >> 7) & 15;  // 16 m-blocks per batch
            const int g     = (n0 >> 5) + tid;
            gnp[((size_t)batch * 32 + g) * 16 + mblk] = make_float2(S, SS);
        }
    }
}

// ---------------------------------------------------------------- attention v3
// lane-local defer-max (shuffles only on trigger) + T5 setprio around MFMA.
__global__ __launch_bounds__(256) void attn_kernel(
    const __bf16* __restrict__ qb, const __bf16* __restrict__ kb,
    const __bf16* __restrict__ vtb, __bf16* __restrict__ aout)
{
    const int bh = blockIdx.x;
    const int sp = 31 - blockIdx.y;          // LPT: longest blocks dispatched first
    const int bb = bh >> 4, hh = bh & 15;
    const __bf16* Q  = qb  + (size_t)bh * T_ * HD_;
    const __bf16* Kp = kb  + (size_t)bh * T_ * HD_;
    const __bf16* VT = vtb + (size_t)bh * HD_ * T_;
    __shared__ __align__(16) __bf16 Qs[2 * 2048];
    __shared__ __align__(16) __bf16 Ks[2][2 * 2048];
    __shared__ __align__(16) __bf16 Vs[2][2 * 2048];
    __shared__ __align__(16) __bf16 Ps[64 * PS_];

    const int tid = threadIdx.x, lane = tid & 63, wv = tid >> 6;
    const int quad = lane >> 4, l16 = lane & 15;
    const int sr = tid >> 2;                              // staging row 0..63
    const int scs = (((tid & 3) ^ ((sr >> 1) & 3)) * 8);  // swizzled stage col
    const int xq8 = (quad ^ ((l16 >> 1) & 3)) * 8;        // swizzled read col

    const int q0 = sp * 64, nkt = sp + 1;

    // prologue: stage Q + K/V tile 0, drain, hoist Q to regs
#pragma unroll
    for (int s = 0; s < 2; ++s) {
        gload_lds16(Q  + (size_t)(q0 + sr) * HD_ + s * 32 + scs, Qs + s * 2048 + tid * 8);
        gload_lds16(Kp + (size_t)sr * HD_ + s * 32 + scs, &Ks[0][s * 2048 + tid * 8]);
        gload_lds16(VT + (size_t)sr * T_  + s * 32 + scs, &Vs[0][s * 2048 + tid * 8]);
    }
    asm volatile("s_waitcnt vmcnt(0)" ::: "memory");
    __builtin_amdgcn_s_barrier();
    __builtin_amdgcn_sched_barrier(0);

    bf16x8 aq[2];
#pragma unroll
    for (int kk = 0; kk < 2; ++kk)
        aq[kk] = *(const bf16x8*)(Qs + kk * 2048 + (wv * 16 + l16) * 32 + xq8);

    float m_i[4], l_p[4];
    floatx4 Ov[4];
    { floatx4 z = {0.f, 0.f, 0.f, 0.f};
#pragma unroll
      for (int i = 0; i < 4; ++i) { Ov[i] = z; m_i[i] = -1e30f; l_p[i] = 0.f; } }

    int cur = 0;
    for (int kt = 0; kt < nkt; ++kt) {
        if (kt + 1 < nkt) {
            const int kn = (kt + 1) * 64;
#pragma unroll
            for (int s = 0; s < 2; ++s) {
                gload_lds16(Kp + (size_t)(kn + sr) * HD_ + s * 32 + scs,
                            &Ks[cur ^ 1][s * 2048 + tid * 8]);
                gload_lds16(VT + (size_t)sr * T_ + kn + s * 32 + scs,
                            &Vs[cur ^ 1][s * 2048 + tid * 8]);
            }
            asm volatile("s_waitcnt vmcnt(4)" ::: "memory");   // tile kt landed
        } else {
            asm volatile("s_waitcnt vmcnt(0)" ::: "memory");
        }
        __builtin_amdgcn_s_barrier();          // all waves: buf[cur] ready
        __builtin_amdgcn_sched_barrier(0);

        const __bf16* Kc = Ks[cur];
        const __bf16* Vc = Vs[cur];

        // S = Q K^T (log2-domain scores)
        floatx4 sacc[4];
        { floatx4 z = {0.f, 0.f, 0.f, 0.f};
#pragma unroll
          for (int i = 0; i < 4; ++i) sacc[i] = z; }
        __builtin_amdgcn_s_setprio(1);
#pragma unroll
        for (int kk = 0; kk < 2; ++kk)
#pragma unroll
            for (int ni = 0; ni < 4; ++ni) {
                const bf16x8 bk = *(const bf16x8*)(Kc + kk * 2048 + (ni * 16 + l16) * 32 + xq8);
                sacc[ni] = __builtin_amdgcn_mfma_f32_16x16x32_bf16(aq[kk], bk, sacc[ni], 0, 0, 0);
            }
        __builtin_amdgcn_s_setprio(0);
        if (kt == sp) {    // diagonal tile: causal mask (local coords)
#pragma unroll
            for (int ni = 0; ni < 4; ++ni) {
                const int keyL = ni * 16 + l16;
#pragma unroll
                for (int r = 0; r < 4; ++r)
                    if (keyL > quad * 4 + r + wv * 16) sacc[ni][r] = -1e30f;
            }
        }
        // defer-max, lane-local trigger: shuffles only when rescale needed
        float rml[4];
#pragma unroll
        for (int r = 0; r < 4; ++r)
            rml[r] = fmaxf(fmaxf(sacc[0][r], sacc[1][r]),
                           fmaxf(sacc[2][r], sacc[3][r]));
        float need = rml[0] - m_i[0];
#pragma unroll
        for (int r = 1; r < 4; ++r) need = fmaxf(need, rml[r] - m_i[r]);
        if (__any(need > 8.f)) {               // rare: exact row max + rescale
#pragma unroll
            for (int off = 1; off < 16; off <<= 1)
#pragma unroll
                for (int r = 0; r < 4; ++r)
                    rml[r] = fmaxf(rml[r], __shfl_xor(rml[r], off, 64));
#pragma unroll
            for (int r = 0; r < 4; ++r) {
                const float mn = fmaxf(m_i[r], rml[r]);
                const float al = exp2f(m_i[r] - mn);
                m_i[r] = mn;
                l_p[r] *= al;
#pragma unroll
                for (int ni = 0; ni < 4; ++ni) Ov[ni][r] *= al;
            }
        }
#pragma unroll
        for (int ni = 0; ni < 4; ++ni)
#pragma unroll
            for (int r = 0; r < 4; ++r) {
                const float pe = exp2f(sacc[ni][r] - m_i[r]);
                sacc[ni][r] = pe;
                l_p[r] += pe;                  // lane-partial; reduced at end
            }
        // P: C-layout -> A-layout via wave-private LDS rows (stride 72)
#pragma unroll
        for (int ni = 0; ni < 4; ++ni)
#pragma unroll
            for (int r = 0; r < 4; ++r)
                Ps[(wv * 16 + quad * 4 + r) * PS_ + ni * 16 + l16] = (__bf16)sacc[ni][r];
        // O += P V
        __builtin_amdgcn_s_setprio(1);
#pragma unroll
        for (int kk = 0; kk < 2; ++kk) {
            const bf16x8 ap = *(const bf16x8*)(Ps + (wv * 16 + l16) * PS_ + kk * 32 + quad * 8);
#pragma unroll
            for (int ni = 0; ni < 4; ++ni) {
                const bf16x8 bv2 = *(const bf16x8*)(Vc + kk * 2048 + (ni * 16 + l16) * 32 + xq8);
                Ov[ni] = __builtin_amdgcn_mfma_f32_16x16x32_bf16(ap, bv2, Ov[ni], 0, 0, 0);
            }
        }
        __builtin_amdgcn_s_setprio(0);
        __builtin_amdgcn_sched_barrier(0);     // keep reads above the barrier
        __builtin_amdgcn_s_barrier();          // reads of buf[cur] done
        __builtin_amdgcn_sched_barrier(0);     // keep next staging below
        cur ^= 1;
    }
    // epilogue: reduce lane-partial l across the 16 key-lanes, then store
#pragma unroll
    for (int off = 1; off < 16; off <<= 1)
#pragma unroll
        for (int r = 0; r < 4; ++r)
            l_p[r] += __shfl_xor(l_p[r], off, 64);
#pragma unroll
    for (int ni = 0; ni < 4; ++ni)
#pragma unroll
        for (int r = 0; r < 4; ++r) {
            const int t = q0 + wv * 16 + quad * 4 + r;
            aout[((size_t)(bb * T_ + t)) * H_ + hh * HD_ + ni * 16 + l16] =
                (__bf16)(Ov[ni][r] / l_p[r]);
        }
}

// ---------------------------------------------------------------- launch
extern "C" void kernel_launch(void* const* d_in, const int* in_sizes, int n_in,
                              void* d_out, int out_size, void* d_ws, size_t ws_size,
                              hipStream_t stream)
{
    (void)in_sizes; (void)n_in; (void)out_size; (void)ws_size;
    const float* x       = (const float*)d_in[0];
    const float* w_attn  = (const float*)d_in[1];
    const float* b_attn  = (const float*)d_in[2];
    const float* w_aproj = (const float*)d_in[3];
    const float* b_aproj = (const float*)d_in[4];
    const float* ln1_w   = (const float*)d_in[5];
    const float* ln1_b   = (const float*)d_in[6];
    const float* ln2_w   = (const float*)d_in[7];
    const float* ln2_b   = (const float*)d_in[8];
    const float* w_fc    = (const float*)d_in[9];
    const float* b_fc    = (const float*)d_in[10];
    const float* w_mproj = (const float*)d_in[11];
    const float* b_mproj = (const float*)d_in[12];
    float* out = (float*)d_out;
    float* present = out + (size_t)M_ * H_;

    char* wp = (char*)d_ws;
    auto alloc = [&](size_t bytes) {
        void* p = (void*)wp; wp += (bytes + 255) & ~(size_t)255; return p;
    };
    __bf16* A1       = (__bf16*)alloc((size_t)M_ * H_ * 2);
    __bf16* A2       = (__bf16*)alloc((size_t)M_ * H_ * 2);
    __bf16* WattnT   = (__bf16*)alloc((size_t)3 * H_ * H_ * 2);
    __bf16* WaprojT  = (__bf16*)alloc((size_t)H_ * H_ * 2);
    __bf16* WfcT     = (__bf16*)alloc((size_t)4 * H_ * H_ * 2);
    __bf16* WmprojT  = (__bf16*)alloc((size_t)4 * H_ * H_ * 2);
    __bf16* qb       = (__bf16*)alloc((size_t)M_ * H_ * 2);
    __bf16* kb       = (__bf16*)alloc((size_t)M_ * H_ * 2);
    __bf16* vb       = (__bf16*)alloc((size_t)M_ * H_ * 2);
    __bf16* vtb      = (__bf16*)alloc((size_t)M_ * H_ * 2);
    __bf16* attn_out = (__bf16*)alloc((size_t)M_ * H_ * 2);
    float*  x2       = (float*) alloc((size_t)M_ * H_ * 4);
    __bf16* Hbuf     = (__bf16*)alloc((size_t)M_ * 4 * H_ * 2);
    float2* gn_part  = (float2*)alloc(64 * 16 * sizeof(float2));

    transpose_bf16<<<dim3(H_/32, 3*H_/32), 256, 0, stream>>>(w_attn,  WattnT,  H_,   3*H_);
    transpose_bf16<<<dim3(H_/32, H_/32),   256, 0, stream>>>(w_aproj, WaprojT, H_,   H_);
    transpose_bf16<<<dim3(H_/32, 4*H_/32), 256, 0, stream>>>(w_fc,    WfcT,    H_,   4*H_);
    transpose_bf16<<<dim3(4*H_/32, H_/32), 256, 0, stream>>>(w_mproj, WmprojT, 4*H_, H_);

    gn_partial<<<dim3(64, 16), 256, 0, stream>>>(x, gn_part);
    gn_apply  <<<M_*H_/1024, 256, 0, stream>>>(x, gn_part, ln1_w, ln1_b, A1);

    gemm_qkv<<<dim3(M_/256, 3*H_/256), 512, 0, stream>>>(A1, WattnT, b_attn,
                                                         qb, kb, vb, present);
    transpose_v<<<dim3(B_*NH_, T_/32, HD_/32), 256, 0, stream>>>(vb, vtb);
    attn_kernel<<<dim3(32, 32), 256, 0, stream>>>(qb, kb, vtb, attn_out);
    gemm_resid_n64<<<dim3(M_/128, H_/64), 256, 0, stream>>>(attn_out, WaprojT, b_aproj,
                                                            x, x2, gn_part, H_, H_);

    gn_apply<<<M_*H_/1024, 256, 0, stream>>>(x2, gn_part, ln2_w, ln2_b, A2);

    gemm_gelu<<<dim3(M_/256, 4*H_/256), 512, 0, stream>>>(A2, WfcT, b_fc, Hbuf);
    gemm_resid_n64<<<dim3(M_/128, H_/64), 256, 0, stream>>>(Hbuf, WmprojT, b_mproj,
                                                            x2, out, nullptr, 4*H_, H_);
}